// Round 7
// baseline (195.818 us; speedup 1.0000x reference)
//
#include <hip/hip_runtime.h>

#define FIX_SCALE 16777216.0f            // 2^24
#define SUM_BITS 44
#define SUM_MASK ((1ull << SUM_BITS) - 1)

// ---------------- fused: hist_rank (blocks [0,hb)) + raw layer-1 GEMM (blocks [hb,..)) ----
// hist part: packed[c] += (1<<44)|fix24(ew); rank[e] = arrival index (from atomic return)
// gemm part: h1[node] = x[node,:16] @ W1   (RAW - no dinv; hides under atomic-bound hist)
__global__ __launch_bounds__(256) void hist_gemm(
        const int* __restrict__ col, const float* __restrict__ ew,
        unsigned long long* __restrict__ packed, int* __restrict__ rank,
        const float* __restrict__ x, const float* __restrict__ W1,
        float* __restrict__ h1, int E, int n, int histBlocks) {
    __shared__ float Ws[16 * 64];
    int t = threadIdx.x;
    if ((int)blockIdx.x < histBlocks) {
        int e = blockIdx.x * 256 + t;
        if (e >= E) return;
        int c = col[e];
        unsigned long long add = (1ull << SUM_BITS) |
                                 (unsigned long long)(ew[e] * FIX_SCALE + 0.5f);
        unsigned long long old = atomicAdd(&packed[c], add);
        rank[e] = (int)(old >> SUM_BITS);
    } else {
        reinterpret_cast<float4*>(Ws)[t] = reinterpret_cast<const float4*>(W1)[t];
        __syncthreads();
        int node = ((int)blockIdx.x - histBlocks) * 256 + t;
        if (node >= n) return;
        float xv[16];
        const float4* xr = reinterpret_cast<const float4*>(x + (size_t)node * 16);
#pragma unroll
        for (int i = 0; i < 4; ++i)
            *reinterpret_cast<float4*>(&xv[i * 4]) = xr[i];   // coalesced
        float4* orow = reinterpret_cast<float4*>(h1 + ((size_t)node << 6));
        for (int jb = 0; jb < 16; ++jb) {
            float4 acc = make_float4(0.f, 0.f, 0.f, 0.f);
#pragma unroll
            for (int k = 0; k < 16; ++k) {
                float hk = xv[k];
                const float4 wv = *reinterpret_cast<const float4*>(&Ws[k * 64 + jb * 4]);
                acc.x += hk * wv.x; acc.y += hk * wv.y;
                acc.z += hk * wv.z; acc.w += hk * wv.w;
            }
            orow[jb] = acc;
        }
    }
}

// ---------------- scan stage 1: per-block (256) exclusive scan of counts ----------------
__global__ void scan1(const unsigned long long* __restrict__ packed, int* __restrict__ start,
                      int* __restrict__ bsum, int n) {
    __shared__ int sd[256];
    int t = threadIdx.x;
    int i = blockIdx.x * 256 + t;
    int v = (i < n) ? (int)(packed[i] >> SUM_BITS) : 0;
    sd[t] = v;
    __syncthreads();
    for (int off = 1; off < 256; off <<= 1) {   // Hillis-Steele inclusive
        int x = (t >= off) ? sd[t - off] : 0;
        __syncthreads();
        sd[t] += x;
        __syncthreads();
    }
    if (i < n) start[i] = sd[t] - v;            // local exclusive
    if (t == 255) bsum[blockIdx.x] = sd[255];   // block total
}

// ---------------- scan stage 2: single block scans block sums (nb <= 1024) ----------------
__global__ void scan2(const int* __restrict__ bsum, int* __restrict__ boff,
                      int* __restrict__ start, int nb, int n) {
    __shared__ int sd[1024];
    int t = threadIdx.x;
    int v = (t < nb) ? bsum[t] : 0;
    sd[t] = v;
    __syncthreads();
    for (int off = 1; off < 1024; off <<= 1) {
        int x = (t >= off) ? sd[t - off] : 0;
        __syncthreads();
        sd[t] += x;
        __syncthreads();
    }
    if (t < nb) boff[t] = sd[t] - v;
    if (t == 1023) start[n] = sd[1023];         // grand total = E
}

// ---------------- scan stage 3: finalize start, compute dinv ----------------
__global__ void scan3(int* __restrict__ start, const int* __restrict__ boff,
                      const unsigned long long* __restrict__ packed,
                      float* __restrict__ dinv, int n) {
    int i = blockIdx.x * blockDim.x + threadIdx.x;
    if (i >= n) return;
    start[i] += boff[i >> 8];                   // scan1 chunk = 256
    float d = (float)(double)(packed[i] & SUM_MASK) * (1.0f / FIX_SCALE) + 1.0f;
    dinv[i] = rsqrtf(d);                        // d >= 1 always (self-loop)
}

// ---------------- edge pass 2: bin edges into CSR (NO atomics), w = ew*dinv[r] ----------
__global__ void bin_edges(const int* __restrict__ row, const int* __restrict__ col,
                          const float* __restrict__ ew, const float* __restrict__ dinv,
                          const int* __restrict__ start, const int* __restrict__ rank,
                          int2* __restrict__ pack, int E) {
    int e = blockIdx.x * blockDim.x + threadIdx.x;
    if (e >= E) return;
    int c = col[e], r = row[e];
    int pos = start[c] + rank[e];
    pack[pos] = make_int2(r, __float_as_int(ew[e] * dinv[r]));
}

// ---------------- dense: g2 = h[N,64] @ W[64,64] (RAW), register-blocked GEMV ----------
__global__ __launch_bounds__(256) void gemm_hid(const float* __restrict__ h,
                                                const float* __restrict__ W,
                                                float* __restrict__ out, int n) {
    __shared__ float Ws[64 * 64];
    int t = threadIdx.x;                       // 256 threads
#pragma unroll
    for (int i = 0; i < 16; ++i) Ws[i * 256 + t] = W[i * 256 + t];
    __syncthreads();
    int node = blockIdx.x * 256 + t;
    if (node >= n) return;
    float hv[64];
    const float4* hr = reinterpret_cast<const float4*>(h + ((size_t)node << 6));
#pragma unroll
    for (int i = 0; i < 16; ++i)
        *reinterpret_cast<float4*>(&hv[i * 4]) = hr[i];
    float4* orow = reinterpret_cast<float4*>(out + ((size_t)node << 6));
    for (int jb = 0; jb < 16; ++jb) {
        float4 acc = make_float4(0.f, 0.f, 0.f, 0.f);
#pragma unroll
        for (int k = 0; k < 64; ++k) {
            float hk = hv[k];
            const float4 wv = *reinterpret_cast<const float4*>(&Ws[k * 64 + jb * 4]);
            acc.x += hk * wv.x; acc.y += hk * wv.y;
            acc.z += hk * wv.z; acc.w += hk * wv.w;
        }
        orow[jb] = acc;
    }
}

// ---------------- shared gather body: 4 subs x float4, 16 edges in flight ----------------
__device__ __forceinline__ float4 gather_acc(const int* __restrict__ start,
                                             const int2* __restrict__ pack,
                                             const float* __restrict__ g,
                                             int wid, int sub, int ch4) {
    int s = start[wid], e = start[wid + 1];
    float4 acc = make_float4(0.f, 0.f, 0.f, 0.f);
    int i = s;
    for (; i + 15 < e; i += 16) {               // 16 edges in flight per wave
        int2 p0 = pack[i + sub];
        int2 p1 = pack[i + 4 + sub];
        int2 p2 = pack[i + 8 + sub];
        int2 p3 = pack[i + 12 + sub];
        float w0 = __int_as_float(p0.y), w1 = __int_as_float(p1.y);
        float w2 = __int_as_float(p2.y), w3 = __int_as_float(p3.y);
        const float4 v0 = *reinterpret_cast<const float4*>(g + ((size_t)p0.x << 6) + ch4);
        const float4 v1 = *reinterpret_cast<const float4*>(g + ((size_t)p1.x << 6) + ch4);
        const float4 v2 = *reinterpret_cast<const float4*>(g + ((size_t)p2.x << 6) + ch4);
        const float4 v3 = *reinterpret_cast<const float4*>(g + ((size_t)p3.x << 6) + ch4);
        acc.x += v0.x * w0; acc.y += v0.y * w0; acc.z += v0.z * w0; acc.w += v0.w * w0;
        acc.x += v1.x * w1; acc.y += v1.y * w1; acc.z += v1.z * w1; acc.w += v1.w * w1;
        acc.x += v2.x * w2; acc.y += v2.y * w2; acc.z += v2.z * w2; acc.w += v2.w * w2;
        acc.x += v3.x * w3; acc.y += v3.y * w3; acc.z += v3.z * w3; acc.w += v3.w * w3;
    }
    if (i + 7 < e) {                            // >= 8 remain
        int2 p0 = pack[i + sub];
        int2 p1 = pack[i + 4 + sub];
        float w0 = __int_as_float(p0.y), w1 = __int_as_float(p1.y);
        const float4 v0 = *reinterpret_cast<const float4*>(g + ((size_t)p0.x << 6) + ch4);
        const float4 v1 = *reinterpret_cast<const float4*>(g + ((size_t)p1.x << 6) + ch4);
        acc.x += v0.x * w0; acc.y += v0.y * w0; acc.z += v0.z * w0; acc.w += v0.w * w0;
        acc.x += v1.x * w1; acc.y += v1.y * w1; acc.z += v1.z * w1; acc.w += v1.w * w1;
        i += 8;
    }
    if (i + 3 < e) {                            // >= 4 remain
        int2 p0 = pack[i + sub];
        float w0 = __int_as_float(p0.y);
        const float4 v0 = *reinterpret_cast<const float4*>(g + ((size_t)p0.x << 6) + ch4);
        acc.x += v0.x * w0; acc.y += v0.y * w0; acc.z += v0.z * w0; acc.w += v0.w * w0;
        i += 4;
    }
    int rem = e - i;                            // 0..3
    if (sub < rem) {
        int2 p0 = pack[i + sub];
        float w0 = __int_as_float(p0.y);
        const float4 v0 = *reinterpret_cast<const float4*>(g + ((size_t)p0.x << 6) + ch4);
        acc.x += v0.x * w0; acc.y += v0.y * w0; acc.z += v0.z * w0; acc.w += v0.w * w0;
    }
#pragma unroll
    for (int m = 16; m <= 32; m <<= 1) {        // reduce across 4 sub groups
        acc.x += __shfl_xor(acc.x, m, 64);
        acc.y += __shfl_xor(acc.y, m, 64);
        acc.z += __shfl_xor(acc.z, m, 64);
        acc.w += __shfl_xor(acc.w, m, 64);
    }
    return acc;
}

// ---------------- gather (mid): h = relu(di*acc + di^2*g[c] + b) ----------------
__global__ __launch_bounds__(256) void gather_mid(const int* __restrict__ start,
                                                  const int2* __restrict__ pack,
                                                  const float* __restrict__ g,
                                                  const float* __restrict__ dinv,
                                                  const float* __restrict__ b,
                                                  float* __restrict__ out, int n) {
    int wid = (blockIdx.x * blockDim.x + threadIdx.x) >> 6;
    if (wid >= n) return;
    int lane = threadIdx.x & 63;
    int sub = lane >> 4;
    int ch4 = (lane & 15) << 2;
    float4 acc = gather_acc(start, pack, g, wid, sub, ch4);
    if (sub == 0) {                              // lanes 0..15 write 256B contiguous
        float di = dinv[wid];
        float d2 = di * di;
        const float4 g0 = *reinterpret_cast<const float4*>(g + ((size_t)wid << 6) + ch4);
        const float4 bb = *reinterpret_cast<const float4*>(b + ch4);
        float4 r;
        r.x = fmaxf(di * acc.x + d2 * g0.x + bb.x, 0.f);
        r.y = fmaxf(di * acc.y + d2 * g0.y + bb.y, 0.f);
        r.z = fmaxf(di * acc.z + d2 * g0.z + bb.z, 0.f);
        r.w = fmaxf(di * acc.w + d2 * g0.w + bb.w, 0.f);
        *reinterpret_cast<float4*>(out + ((size_t)wid << 6) + ch4) = r;
    }
}

// ---------------- gather (final) + head fused: out[c,0:2] ----------------
__global__ __launch_bounds__(256) void gather_head(const int* __restrict__ start,
                                                   const int2* __restrict__ pack,
                                                   const float* __restrict__ g,
                                                   const float* __restrict__ dinv,
                                                   const float* __restrict__ b,
                                                   const float* __restrict__ Wl,
                                                   const float* __restrict__ bl,
                                                   float* __restrict__ out, int n) {
    int wid = (blockIdx.x * blockDim.x + threadIdx.x) >> 6;
    if (wid >= n) return;
    int lane = threadIdx.x & 63;
    int sub = lane >> 4;
    int ch4 = (lane & 15) << 2;
    float4 acc = gather_acc(start, pack, g, wid, sub, ch4);
    if (sub == 0) {
        float di = dinv[wid];
        float d2 = di * di;
        const float4 g0 = *reinterpret_cast<const float4*>(g + ((size_t)wid << 6) + ch4);
        const float4 bb = *reinterpret_cast<const float4*>(b + ch4);
        float4 h;
        h.x = fmaxf(di * acc.x + d2 * g0.x + bb.x, 0.f);
        h.y = fmaxf(di * acc.y + d2 * g0.y + bb.y, 0.f);
        h.z = fmaxf(di * acc.z + d2 * g0.z + bb.z, 0.f);
        h.w = fmaxf(di * acc.w + d2 * g0.w + bb.w, 0.f);
        float s0 = h.x * Wl[(ch4 + 0) * 2] + h.y * Wl[(ch4 + 1) * 2] +
                   h.z * Wl[(ch4 + 2) * 2] + h.w * Wl[(ch4 + 3) * 2];
        float s1 = h.x * Wl[(ch4 + 0) * 2 + 1] + h.y * Wl[(ch4 + 1) * 2 + 1] +
                   h.z * Wl[(ch4 + 2) * 2 + 1] + h.w * Wl[(ch4 + 3) * 2 + 1];
#pragma unroll
        for (int m = 1; m <= 8; m <<= 1) {       // reduce across lanes 0..15
            s0 += __shfl_xor(s0, m, 64);
            s1 += __shfl_xor(s1, m, 64);
        }
        if (lane == 0) {
            out[(size_t)wid * 2 + 0] = s0 + bl[0];
            out[(size_t)wid * 2 + 1] = s1 + bl[1];
        }
    }
}

extern "C" void kernel_launch(void* const* d_in, const int* in_sizes, int n_in,
                              void* d_out, int out_size, void* d_ws, size_t ws_size,
                              hipStream_t stream) {
    const float* x  = (const float*)d_in[0];
    const int*   ei = (const int*)d_in[1];
    const float* ew = (const float*)d_in[2];
    const float* W1 = (const float*)d_in[3];
    const float* b1 = (const float*)d_in[4];
    const float* W2 = (const float*)d_in[5];
    const float* b2 = (const float*)d_in[6];
    const float* Wl = (const float*)d_in[7];
    const float* bl = (const float*)d_in[8];
    float* out = (float*)d_out;

    const int N = in_sizes[0] / 16;
    const int E = in_sizes[2];
    const int* row = ei;
    const int* col = ei + E;
    const int NB  = (N + 255) / 256;             // node-pass blocks (scan1 / gemm)
    const int NBE = (E + 255) / 256;             // edge-pass blocks

    // workspace layout (8B-aligned first)
    char* p = (char*)d_ws;
    int2*  pack   = (int2*)p;   p += (size_t)E * 8;
    unsigned long long* packed = (unsigned long long*)p; p += (size_t)N * 8;
    float* bufA   = (float*)p;  p += (size_t)N * 64 * 4;   // h1 raw / g2 raw
    float* bufB   = (float*)p;  p += (size_t)N * 64 * 4;   // h (mid) ; rank alias
    float* dinv   = (float*)p;  p += (size_t)N * 4;
    int*   startO = (int*)p;    p += (size_t)(N + 1) * 4;
    int*   bsum   = (int*)p;    p += (size_t)NB * 4;
    int*   boff   = (int*)p;    p += (size_t)NB * 4;
    int*   rank   = (int*)bufB; // alias: bufB dead until gather_mid writes it

    // ---- fused: histogram/rank (atomic-bound) + raw layer-1 GEMM (hides under it) ----
    hipMemsetAsync(packed, 0, (size_t)N * 8, stream);
    hist_gemm<<<NBE + NB, 256, 0, stream>>>(col, ew, packed, rank, x, W1, bufA, E, N, NBE);

    // ---- scan + dinv ----
    scan1<<<NB, 256, 0, stream>>>(packed, startO, bsum, N);
    scan2<<<1, 1024, 0, stream>>>(bsum, boff, startO, NB, N);
    scan3<<<NB, 256, 0, stream>>>(startO, boff, packed, dinv, N);

    // ---- bin edges (atomic-free; folds dinv[r] into weight) ----
    bin_edges<<<NBE, 256, 0, stream>>>(row, col, ew, dinv, startO, rank, pack, E);

    // ---- layer 1 aggregate + relu -> h ----
    gather_mid<<<(N + 3) / 4, 256, 0, stream>>>(startO, pack, bufA, dinv, b1, bufB, N);

    // ---- layer 2 GEMM: g2 = h@W2 (raw) ----
    gemm_hid<<<NB, 256, 0, stream>>>(bufB, W2, bufA, N);

    // ---- layer 2 aggregate + relu + head -> out ----
    gather_head<<<(N + 3) / 4, 256, 0, stream>>>(startO, pack, bufA, dinv, b2, Wl, bl, out, N);
}

// Round 8
// 192.894 us; speedup vs baseline: 1.0152x; 1.0152x over previous
//
#include <hip/hip_runtime.h>

#define FIX_SCALE 16777216.0f            // 2^24
#define SUM_BITS 44
#define SUM_MASK ((1ull << SUM_BITS) - 1)
#define PAD 16                           // u64 stride: one counter per 128B line

// ---------------- edge pass 1: packed count+degree atomic (padded), emit rank ----------
__global__ void hist_rank(const int* __restrict__ col, const float* __restrict__ ew,
                          unsigned long long* __restrict__ packed,
                          int* __restrict__ rank, int E) {
    int e = blockIdx.x * blockDim.x + threadIdx.x;
    if (e >= E) return;
    int c = col[e];
    unsigned long long add = (1ull << SUM_BITS) |
                             (unsigned long long)(ew[e] * FIX_SCALE + 0.5f);
    unsigned long long old = atomicAdd(&packed[(size_t)c * PAD], add);
    rank[e] = (int)(old >> SUM_BITS);    // this edge's arrival index at node c
}

// ---------------- scan stage 1: per-block (256) exclusive scan of counts ----------------
__global__ void scan1(const unsigned long long* __restrict__ packed, int* __restrict__ start,
                      int* __restrict__ bsum, int n) {
    __shared__ int sd[256];
    int t = threadIdx.x;
    int i = blockIdx.x * 256 + t;
    int v = (i < n) ? (int)(packed[(size_t)i * PAD] >> SUM_BITS) : 0;
    sd[t] = v;
    __syncthreads();
    for (int off = 1; off < 256; off <<= 1) {   // Hillis-Steele inclusive
        int x = (t >= off) ? sd[t - off] : 0;
        __syncthreads();
        sd[t] += x;
        __syncthreads();
    }
    if (i < n) start[i] = sd[t] - v;            // local exclusive
    if (t == 255) bsum[blockIdx.x] = sd[255];   // block total
}

// ---------------- scan stage 2: single block scans block sums (nb <= 1024) ----------------
__global__ void scan2(const int* __restrict__ bsum, int* __restrict__ boff,
                      int* __restrict__ start, int nb, int n) {
    __shared__ int sd[1024];
    int t = threadIdx.x;
    int v = (t < nb) ? bsum[t] : 0;
    sd[t] = v;
    __syncthreads();
    for (int off = 1; off < 1024; off <<= 1) {
        int x = (t >= off) ? sd[t - off] : 0;
        __syncthreads();
        sd[t] += x;
        __syncthreads();
    }
    if (t < nb) boff[t] = sd[t] - v;
    if (t == 1023) start[n] = sd[1023];         // grand total = E
}

// ---------------- scan stage 3: finalize start, compute dinv ----------------
__global__ void scan3(int* __restrict__ start, const int* __restrict__ boff,
                      const unsigned long long* __restrict__ packed,
                      float* __restrict__ dinv, int n) {
    int i = blockIdx.x * blockDim.x + threadIdx.x;
    if (i >= n) return;
    start[i] += boff[i >> 8];                   // scan1 chunk = 256
    float d = (float)(double)(packed[(size_t)i * PAD] & SUM_MASK) * (1.0f / FIX_SCALE) + 1.0f;
    dinv[i] = rsqrtf(d);                        // d >= 1 always (self-loop)
}

// ---------------- fused: gemm_in16 (blocks [0,gb)) + bin_edges (blocks [gb,..)) ----------
// gemm part: g1[node] = dinv[node] * (x[node,:16] @ W1)   (thread = node, W1 in LDS)
// bin part:  pack[start[c]+rank[e]] = (row, ew)           (no atomics, no dinv)
__global__ __launch_bounds__(256) void gemm16_bin(
        const float* __restrict__ x, const float* __restrict__ W1,
        const float* __restrict__ dinv, float* __restrict__ g1,
        const int* __restrict__ row, const int* __restrict__ col,
        const float* __restrict__ ew, const int* __restrict__ start,
        const int* __restrict__ rank, int2* __restrict__ pack,
        int n, int E, int gemmBlocks) {
    __shared__ float Ws[16 * 64];
    int t = threadIdx.x;
    if ((int)blockIdx.x < gemmBlocks) {
        reinterpret_cast<float4*>(Ws)[t] = reinterpret_cast<const float4*>(W1)[t];
        __syncthreads();
        int node = blockIdx.x * 256 + t;
        if (node >= n) return;
        float xv[16];
        const float4* xr = reinterpret_cast<const float4*>(x + (size_t)node * 16);
#pragma unroll
        for (int i = 0; i < 4; ++i)
            *reinterpret_cast<float4*>(&xv[i * 4]) = xr[i];   // coalesced
        float di = dinv[node];
        float4* orow = reinterpret_cast<float4*>(g1 + ((size_t)node << 6));
        for (int jb = 0; jb < 16; ++jb) {
            float4 acc = make_float4(0.f, 0.f, 0.f, 0.f);
#pragma unroll
            for (int k = 0; k < 16; ++k) {
                float hk = xv[k];
                const float4 wv = *reinterpret_cast<const float4*>(&Ws[k * 64 + jb * 4]);
                acc.x += hk * wv.x; acc.y += hk * wv.y;
                acc.z += hk * wv.z; acc.w += hk * wv.w;
            }
            acc.x *= di; acc.y *= di; acc.z *= di; acc.w *= di;
            orow[jb] = acc;
        }
    } else {
        int e = ((int)blockIdx.x - gemmBlocks) * 256 + t;
        if (e >= E) return;
        int c = col[e];
        int pos = start[c] + rank[e];
        pack[pos] = make_int2(row[e], __float_as_int(ew[e]));
    }
}

// ---------------- dense: h[N,64] @ W[64,64] -> g2 = dinv*(h@W2) ----------------
__global__ __launch_bounds__(256) void gemm_hid(const float* __restrict__ h,
                                                const float* __restrict__ W,
                                                const float* __restrict__ dinv,
                                                float* __restrict__ out, int n) {
    __shared__ float Ws[64 * 64];
    int t = threadIdx.x;                       // 256 threads
#pragma unroll
    for (int i = 0; i < 16; ++i) Ws[i * 256 + t] = W[i * 256 + t];
    __syncthreads();
    int node = blockIdx.x * 256 + t;
    if (node >= n) return;
    float hv[64];
    const float4* hr = reinterpret_cast<const float4*>(h + ((size_t)node << 6));
#pragma unroll
    for (int i = 0; i < 16; ++i)
        *reinterpret_cast<float4*>(&hv[i * 4]) = hr[i];
    float di = dinv[node];
    float4* orow = reinterpret_cast<float4*>(out + ((size_t)node << 6));
    for (int jb = 0; jb < 16; ++jb) {
        float4 acc = make_float4(0.f, 0.f, 0.f, 0.f);
#pragma unroll
        for (int k = 0; k < 64; ++k) {
            float hk = hv[k];
            const float4 wv = *reinterpret_cast<const float4*>(&Ws[k * 64 + jb * 4]);
            acc.x += hk * wv.x; acc.y += hk * wv.y;
            acc.z += hk * wv.z; acc.w += hk * wv.w;
        }
        acc.x *= di; acc.y *= di; acc.z *= di; acc.w *= di;
        orow[jb] = acc;
    }
}

// ---------------- shared gather body: 4 subs x float4, 8 edges in flight ----------------
__device__ __forceinline__ float4 gather_acc(const int* __restrict__ start,
                                             const int2* __restrict__ pack,
                                             const float* __restrict__ g,
                                             int wid, int sub, int ch4) {
    int s = start[wid], e = start[wid + 1];
    float4 acc = make_float4(0.f, 0.f, 0.f, 0.f);
    int i = s;
    for (; i + 7 < e; i += 8) {                 // 8 edges in flight per wave
        int2 pa = pack[i + sub];
        int2 pb = pack[i + 4 + sub];
        float wa = __int_as_float(pa.y), wb = __int_as_float(pb.y);
        const float4 va = *reinterpret_cast<const float4*>(g + ((size_t)pa.x << 6) + ch4);
        const float4 vb = *reinterpret_cast<const float4*>(g + ((size_t)pb.x << 6) + ch4);
        acc.x += va.x * wa; acc.y += va.y * wa; acc.z += va.z * wa; acc.w += va.w * wa;
        acc.x += vb.x * wb; acc.y += vb.y * wb; acc.z += vb.z * wb; acc.w += vb.w * wb;
    }
    if (i + 3 < e) {                            // >=4 remain
        int2 pa = pack[i + sub];
        float wa = __int_as_float(pa.y);
        const float4 va = *reinterpret_cast<const float4*>(g + ((size_t)pa.x << 6) + ch4);
        acc.x += va.x * wa; acc.y += va.y * wa; acc.z += va.z * wa; acc.w += va.w * wa;
        i += 4;
    }
    int rem = e - i;                            // 0..3
    if (sub < rem) {
        int2 pa = pack[i + sub];
        float wa = __int_as_float(pa.y);
        const float4 va = *reinterpret_cast<const float4*>(g + ((size_t)pa.x << 6) + ch4);
        acc.x += va.x * wa; acc.y += va.y * wa; acc.z += va.z * wa; acc.w += va.w * wa;
    }
#pragma unroll
    for (int m = 16; m <= 32; m <<= 1) {        // reduce across 4 sub groups
        acc.x += __shfl_xor(acc.x, m, 64);
        acc.y += __shfl_xor(acc.y, m, 64);
        acc.z += __shfl_xor(acc.z, m, 64);
        acc.w += __shfl_xor(acc.w, m, 64);
    }
    return acc;
}

// ---------------- gather (mid layer): h_out = relu(di*(acc + g[c]) + b) ----------------
__global__ __launch_bounds__(256) void gather_mid(const int* __restrict__ start,
                                                  const int2* __restrict__ pack,
                                                  const float* __restrict__ g,
                                                  const float* __restrict__ dinv,
                                                  const float* __restrict__ b,
                                                  float* __restrict__ out, int n) {
    int wid = (blockIdx.x * blockDim.x + threadIdx.x) >> 6;
    if (wid >= n) return;
    int lane = threadIdx.x & 63;
    int sub = lane >> 4;
    int ch4 = (lane & 15) << 2;
    float4 acc = gather_acc(start, pack, g, wid, sub, ch4);
    if (sub == 0) {                              // lanes 0..15 write 256B contiguous
        float di = dinv[wid];
        const float4 g0 = *reinterpret_cast<const float4*>(g + ((size_t)wid << 6) + ch4);
        const float4 bb = *reinterpret_cast<const float4*>(b + ch4);
        float4 r;
        r.x = fmaxf(di * (acc.x + g0.x) + bb.x, 0.f);
        r.y = fmaxf(di * (acc.y + g0.y) + bb.y, 0.f);
        r.z = fmaxf(di * (acc.z + g0.z) + bb.z, 0.f);
        r.w = fmaxf(di * (acc.w + g0.w) + bb.w, 0.f);
        *reinterpret_cast<float4*>(out + ((size_t)wid << 6) + ch4) = r;
    }
}

// ---------------- gather (final layer) + head fused: out[c,0:2] ----------------
__global__ __launch_bounds__(256) void gather_head(const int* __restrict__ start,
                                                   const int2* __restrict__ pack,
                                                   const float* __restrict__ g,
                                                   const float* __restrict__ dinv,
                                                   const float* __restrict__ b,
                                                   const float* __restrict__ Wl,
                                                   const float* __restrict__ bl,
                                                   float* __restrict__ out, int n) {
    int wid = (blockIdx.x * blockDim.x + threadIdx.x) >> 6;
    if (wid >= n) return;
    int lane = threadIdx.x & 63;
    int sub = lane >> 4;
    int ch4 = (lane & 15) << 2;
    float4 acc = gather_acc(start, pack, g, wid, sub, ch4);
    if (sub == 0) {
        float di = dinv[wid];
        const float4 g0 = *reinterpret_cast<const float4*>(g + ((size_t)wid << 6) + ch4);
        const float4 bb = *reinterpret_cast<const float4*>(b + ch4);
        float4 h;
        h.x = fmaxf(di * (acc.x + g0.x) + bb.x, 0.f);
        h.y = fmaxf(di * (acc.y + g0.y) + bb.y, 0.f);
        h.z = fmaxf(di * (acc.z + g0.z) + bb.z, 0.f);
        h.w = fmaxf(di * (acc.w + g0.w) + bb.w, 0.f);
        // head: s0/s1 partials over this lane's 4 channels
        float s0 = h.x * Wl[(ch4 + 0) * 2] + h.y * Wl[(ch4 + 1) * 2] +
                   h.z * Wl[(ch4 + 2) * 2] + h.w * Wl[(ch4 + 3) * 2];
        float s1 = h.x * Wl[(ch4 + 0) * 2 + 1] + h.y * Wl[(ch4 + 1) * 2 + 1] +
                   h.z * Wl[(ch4 + 2) * 2 + 1] + h.w * Wl[(ch4 + 3) * 2 + 1];
#pragma unroll
        for (int m = 1; m <= 8; m <<= 1) {       // reduce across lanes 0..15
            s0 += __shfl_xor(s0, m, 64);
            s1 += __shfl_xor(s1, m, 64);
        }
        if (lane == 0) {
            out[(size_t)wid * 2 + 0] = s0 + bl[0];
            out[(size_t)wid * 2 + 1] = s1 + bl[1];
        }
    }
}

extern "C" void kernel_launch(void* const* d_in, const int* in_sizes, int n_in,
                              void* d_out, int out_size, void* d_ws, size_t ws_size,
                              hipStream_t stream) {
    const float* x  = (const float*)d_in[0];
    const int*   ei = (const int*)d_in[1];
    const float* ew = (const float*)d_in[2];
    const float* W1 = (const float*)d_in[3];
    const float* b1 = (const float*)d_in[4];
    const float* W2 = (const float*)d_in[5];
    const float* b2 = (const float*)d_in[6];
    const float* Wl = (const float*)d_in[7];
    const float* bl = (const float*)d_in[8];
    float* out = (float*)d_out;

    const int N = in_sizes[0] / 16;
    const int E = in_sizes[2];
    const int* row = ei;
    const int* col = ei + E;
    const int NB  = (N + 255) / 256;             // scan1 / gemm blocks
    const int NBE = (E + 255) / 256;             // edge-pass blocks

    // workspace layout. packed (N*PAD*8 = 8MB) and pack (E*8 = 8MB) have disjoint
    // lifetimes: packed dies after scan3; pack is born at gemm16_bin. They alias.
    char* p = (char*)d_ws;
    size_t region0 = (size_t)E * 8;
    if ((size_t)N * PAD * 8 > region0) region0 = (size_t)N * PAD * 8;
    int2*  pack   = (int2*)p;
    unsigned long long* packed = (unsigned long long*)p;
    p += region0;
    float* bufA   = (float*)p;  p += (size_t)N * 64 * 4;   // g1 / g2
    float* bufB   = (float*)p;  p += (size_t)N * 64 * 4;   // h (mid) ; rank alias
    float* dinv   = (float*)p;  p += (size_t)N * 4;
    int*   startO = (int*)p;    p += (size_t)(N + 1) * 4;
    int*   bsum   = (int*)p;    p += (size_t)NB * 4;
    int*   boff   = (int*)p;    p += (size_t)NB * 4;
    int*   rank   = (int*)bufB; // alias: bufB dead until gather_mid writes it

    // ---- CSR build + dinv (shared by both layers) ----
    hipMemsetAsync(packed, 0, (size_t)N * PAD * 8, stream);
    hist_rank<<<NBE, 256, 0, stream>>>(col, ew, packed, rank, E);
    scan1<<<NB, 256, 0, stream>>>(packed, startO, bsum, N);
    scan2<<<1, 1024, 0, stream>>>(bsum, boff, startO, NB, N);
    scan3<<<NB, 256, 0, stream>>>(startO, boff, packed, dinv, N);

    // ---- fused: layer-1 GEMM (g1 = dinv*(x@W1)) + edge binning ----
    gemm16_bin<<<NB + NBE, 256, 0, stream>>>(x, W1, dinv, bufA,
                                             row, col, ew, startO, rank, pack,
                                             N, E, NB);

    // ---- layer 1 aggregate + relu -> h ----
    gather_mid<<<(N + 3) / 4, 256, 0, stream>>>(startO, pack, bufA, dinv, b1, bufB, N);

    // ---- layer 2 GEMM: g2 = dinv*(h@W2) ----
    gemm_hid<<<NB, 256, 0, stream>>>(bufB, W2, dinv, bufA, N);

    // ---- layer 2 aggregate + relu + head -> out ----
    gather_head<<<(N + 3) / 4, 256, 0, stream>>>(startO, pack, bufA, dinv, b2, Wl, bl, out, N);
}

// Round 9
// 156.455 us; speedup vs baseline: 1.2516x; 1.2329x over previous
//
#include <hip/hip_runtime.h>

#define NSB 1024                          // scatter blocks (edge chunks)
#define NBUCK(n) ((n) >> 8)               // 256 for N=65536

// ---------------- S1: per-(block,bucket) histogram of col>>8, no global atomics ----------
__global__ __launch_bounds__(256) void s1_hist(const int* __restrict__ col,
                                               int* __restrict__ F, int E, int chunk) {
    __shared__ int cnt[256];
    int t = threadIdx.x, b = blockIdx.x;
    cnt[t] = 0;
    __syncthreads();
    int s = b * chunk, e = min(E, s + chunk);
    for (int i = s + t; i < e; i += 256) atomicAdd(&cnt[col[i] >> 8], 1);   // LDS atomic
    __syncthreads();
    F[t * NSB + b] = cnt[t];              // bucket-major: F[bucket*NSB + block]
}

// ---------------- scan of F (256K entries): 3 stages ----------------
__global__ void scanF1(int* __restrict__ F, int* __restrict__ bsum, int n) {
    __shared__ int sd[256];
    int t = threadIdx.x, i = blockIdx.x * 256 + t;
    int v = (i < n) ? F[i] : 0;
    sd[t] = v;
    __syncthreads();
    for (int o = 1; o < 256; o <<= 1) {
        int x = (t >= o) ? sd[t - o] : 0;
        __syncthreads();
        sd[t] += x;
        __syncthreads();
    }
    if (i < n) F[i] = sd[t] - v;          // local exclusive, in place
    if (t == 255) bsum[blockIdx.x] = sd[255];
}

__global__ void scanF2(const int* __restrict__ bsum, int* __restrict__ boff, int nb) {
    __shared__ int sd[1024];
    int t = threadIdx.x;
    int v = (t < nb) ? bsum[t] : 0;
    sd[t] = v;
    __syncthreads();
    for (int o = 1; o < 1024; o <<= 1) {
        int x = (t >= o) ? sd[t - o] : 0;
        __syncthreads();
        sd[t] += x;
        __syncthreads();
    }
    if (t < nb) boff[t] = sd[t] - v;
}

__global__ void scanF3(int* __restrict__ F, const int* __restrict__ boff, int n) {
    int i = blockIdx.x * blockDim.x + threadIdx.x;
    if (i < n) F[i] += boff[i >> 8];
}

// ---------------- S3: scatter edges into bucket-grouped tmp (LDS rank atomics only) -----
// tmp[pos] = (row | fine<<16, ew_bits)
__global__ __launch_bounds__(256) void s3_scatter(const int* __restrict__ col,
                                                  const int* __restrict__ row,
                                                  const float* __restrict__ ew,
                                                  const int* __restrict__ F,
                                                  int2* __restrict__ tmp, int E, int chunk) {
    __shared__ int off[256];
    __shared__ int cur[256];
    int t = threadIdx.x, b = blockIdx.x;
    off[t] = F[t * NSB + b];
    cur[t] = 0;
    __syncthreads();
    int s = b * chunk, e = min(E, s + chunk);
    for (int i = s + t; i < e; i += 256) {
        int c = col[i];
        int bk = c >> 8;
        int rk = atomicAdd(&cur[bk], 1);  // LDS returning atomic (cheap)
        tmp[off[bk] + rk] = make_int2(row[i] | ((c & 255) << 16), __float_as_int(ew[i]));
    }
}

// ---------------- S4: per-bucket fine sort -> pack/start/dinv + fused layer-1 GEMV ------
// block b owns bucket b (nodes b*256..b*256+255); thread t owns node c = b*256+t.
__global__ __launch_bounds__(256) void s4_fine(const int2* __restrict__ tmp,
                                               const int* __restrict__ F,
                                               int2* __restrict__ pack,
                                               float* __restrict__ dinv,
                                               int* __restrict__ start,
                                               const float* __restrict__ x,
                                               const float* __restrict__ W1,
                                               float* __restrict__ g1,
                                               int n, int E, int nbuck) {
    __shared__ int   fcnt[256];
    __shared__ float fdeg[256];
    __shared__ int   foff[256];
    __shared__ int   fcur[256];
    __shared__ float Ws[16 * 64];
    int t = threadIdx.x, b = blockIdx.x;
    reinterpret_cast<float4*>(Ws)[t] = reinterpret_cast<const float4*>(W1)[t];  // 4KB
    fcnt[t] = 0; fdeg[t] = 0.f; fcur[t] = 0;
    __syncthreads();
    int segS = F[b * NSB];
    int segE = (b == nbuck - 1) ? E : F[(b + 1) * NSB];
    for (int i = segS + t; i < segE; i += 256) {
        int2 v = tmp[i];
        int f = (v.x >> 16) & 255;
        atomicAdd(&fcnt[f], 1);
        atomicAdd(&fdeg[f], __int_as_float(v.y));   // LDS float atomic
    }
    __syncthreads();
    int val = fcnt[t];
    foff[t] = val;
    __syncthreads();
    for (int o = 1; o < 256; o <<= 1) {             // Hillis-Steele inclusive
        int xk = (t >= o) ? foff[t - o] : 0;
        __syncthreads();
        foff[t] += xk;
        __syncthreads();
    }
    int excl = foff[t] - val;
    int c = (b << 8) | t;
    float di = rsqrtf(fdeg[t] + 1.0f);              // + self-loop; deg>=1 always
    if (c < n) {
        dinv[c]  = di;
        start[c] = segS + excl;
    }
    if (b == nbuck - 1 && t == 255) start[n] = E;
    __syncthreads();
    foff[t] = excl;
    __syncthreads();
    for (int i = segS + t; i < segE; i += 256) {    // scatter to final CSR slots
        int2 v = tmp[i];
        int f = (v.x >> 16) & 255;
        int rk = atomicAdd(&fcur[f], 1);
        pack[segS + foff[f] + rk] = make_int2(v.x & 0xFFFF, v.y);
    }
    // ---- fused layer-1 GEMV: g1[c] = di * (x[c,:16] @ W1) ----
    if (c >= n) return;
    float xv[16];
    const float4* xr = reinterpret_cast<const float4*>(x + (size_t)c * 16);
#pragma unroll
    for (int i = 0; i < 4; ++i)
        *reinterpret_cast<float4*>(&xv[i * 4]) = xr[i];
    float4* orow = reinterpret_cast<float4*>(g1 + ((size_t)c << 6));
    for (int jb = 0; jb < 16; ++jb) {
        float4 acc = make_float4(0.f, 0.f, 0.f, 0.f);
#pragma unroll
        for (int k = 0; k < 16; ++k) {
            float hk = xv[k];
            const float4 wv = *reinterpret_cast<const float4*>(&Ws[k * 64 + jb * 4]);
            acc.x += hk * wv.x; acc.y += hk * wv.y;
            acc.z += hk * wv.z; acc.w += hk * wv.w;
        }
        acc.x *= di; acc.y *= di; acc.z *= di; acc.w *= di;
        orow[jb] = acc;
    }
}

// ---------------- dense: h[N,64] @ W[64,64] -> g2 = dinv*(h@W2) ----------------
__global__ __launch_bounds__(256) void gemm_hid(const float* __restrict__ h,
                                                const float* __restrict__ W,
                                                const float* __restrict__ dinv,
                                                float* __restrict__ out, int n) {
    __shared__ float Ws[64 * 64];
    int t = threadIdx.x;
#pragma unroll
    for (int i = 0; i < 16; ++i) Ws[i * 256 + t] = W[i * 256 + t];
    __syncthreads();
    int node = blockIdx.x * 256 + t;
    if (node >= n) return;
    float hv[64];
    const float4* hr = reinterpret_cast<const float4*>(h + ((size_t)node << 6));
#pragma unroll
    for (int i = 0; i < 16; ++i)
        *reinterpret_cast<float4*>(&hv[i * 4]) = hr[i];
    float di = dinv[node];
    float4* orow = reinterpret_cast<float4*>(out + ((size_t)node << 6));
    for (int jb = 0; jb < 16; ++jb) {
        float4 acc = make_float4(0.f, 0.f, 0.f, 0.f);
#pragma unroll
        for (int k = 0; k < 64; ++k) {
            float hk = hv[k];
            const float4 wv = *reinterpret_cast<const float4*>(&Ws[k * 64 + jb * 4]);
            acc.x += hk * wv.x; acc.y += hk * wv.y;
            acc.z += hk * wv.z; acc.w += hk * wv.w;
        }
        acc.x *= di; acc.y *= di; acc.z *= di; acc.w *= di;
        orow[jb] = acc;
    }
}

// ---------------- shared gather body: 4 subs x float4, 8 edges in flight ----------------
__device__ __forceinline__ float4 gather_acc(const int* __restrict__ start,
                                             const int2* __restrict__ pack,
                                             const float* __restrict__ g,
                                             int wid, int sub, int ch4) {
    int s = start[wid], e = start[wid + 1];
    float4 acc = make_float4(0.f, 0.f, 0.f, 0.f);
    int i = s;
    for (; i + 7 < e; i += 8) {
        int2 pa = pack[i + sub];
        int2 pb = pack[i + 4 + sub];
        float wa = __int_as_float(pa.y), wb = __int_as_float(pb.y);
        const float4 va = *reinterpret_cast<const float4*>(g + ((size_t)pa.x << 6) + ch4);
        const float4 vb = *reinterpret_cast<const float4*>(g + ((size_t)pb.x << 6) + ch4);
        acc.x += va.x * wa; acc.y += va.y * wa; acc.z += va.z * wa; acc.w += va.w * wa;
        acc.x += vb.x * wb; acc.y += vb.y * wb; acc.z += vb.z * wb; acc.w += vb.w * wb;
    }
    if (i + 3 < e) {
        int2 pa = pack[i + sub];
        float wa = __int_as_float(pa.y);
        const float4 va = *reinterpret_cast<const float4*>(g + ((size_t)pa.x << 6) + ch4);
        acc.x += va.x * wa; acc.y += va.y * wa; acc.z += va.z * wa; acc.w += va.w * wa;
        i += 4;
    }
    int rem = e - i;
    if (sub < rem) {
        int2 pa = pack[i + sub];
        float wa = __int_as_float(pa.y);
        const float4 va = *reinterpret_cast<const float4*>(g + ((size_t)pa.x << 6) + ch4);
        acc.x += va.x * wa; acc.y += va.y * wa; acc.z += va.z * wa; acc.w += va.w * wa;
    }
#pragma unroll
    for (int m = 16; m <= 32; m <<= 1) {
        acc.x += __shfl_xor(acc.x, m, 64);
        acc.y += __shfl_xor(acc.y, m, 64);
        acc.z += __shfl_xor(acc.z, m, 64);
        acc.w += __shfl_xor(acc.w, m, 64);
    }
    return acc;
}

// ---------------- gather (mid layer): h_out = relu(di*(acc + g[c]) + b) ----------------
__global__ __launch_bounds__(256) void gather_mid(const int* __restrict__ start,
                                                  const int2* __restrict__ pack,
                                                  const float* __restrict__ g,
                                                  const float* __restrict__ dinv,
                                                  const float* __restrict__ b,
                                                  float* __restrict__ out, int n) {
    int wid = (blockIdx.x * blockDim.x + threadIdx.x) >> 6;
    if (wid >= n) return;
    int lane = threadIdx.x & 63;
    int sub = lane >> 4;
    int ch4 = (lane & 15) << 2;
    float4 acc = gather_acc(start, pack, g, wid, sub, ch4);
    if (sub == 0) {
        float di = dinv[wid];
        const float4 g0 = *reinterpret_cast<const float4*>(g + ((size_t)wid << 6) + ch4);
        const float4 bb = *reinterpret_cast<const float4*>(b + ch4);
        float4 r;
        r.x = fmaxf(di * (acc.x + g0.x) + bb.x, 0.f);
        r.y = fmaxf(di * (acc.y + g0.y) + bb.y, 0.f);
        r.z = fmaxf(di * (acc.z + g0.z) + bb.z, 0.f);
        r.w = fmaxf(di * (acc.w + g0.w) + bb.w, 0.f);
        *reinterpret_cast<float4*>(out + ((size_t)wid << 6) + ch4) = r;
    }
}

// ---------------- gather (final layer) + head fused: out[c,0:2] ----------------
__global__ __launch_bounds__(256) void gather_head(const int* __restrict__ start,
                                                   const int2* __restrict__ pack,
                                                   const float* __restrict__ g,
                                                   const float* __restrict__ dinv,
                                                   const float* __restrict__ b,
                                                   const float* __restrict__ Wl,
                                                   const float* __restrict__ bl,
                                                   float* __restrict__ out, int n) {
    int wid = (blockIdx.x * blockDim.x + threadIdx.x) >> 6;
    if (wid >= n) return;
    int lane = threadIdx.x & 63;
    int sub = lane >> 4;
    int ch4 = (lane & 15) << 2;
    float4 acc = gather_acc(start, pack, g, wid, sub, ch4);
    if (sub == 0) {
        float di = dinv[wid];
        const float4 g0 = *reinterpret_cast<const float4*>(g + ((size_t)wid << 6) + ch4);
        const float4 bb = *reinterpret_cast<const float4*>(b + ch4);
        float4 h;
        h.x = fmaxf(di * (acc.x + g0.x) + bb.x, 0.f);
        h.y = fmaxf(di * (acc.y + g0.y) + bb.y, 0.f);
        h.z = fmaxf(di * (acc.z + g0.z) + bb.z, 0.f);
        h.w = fmaxf(di * (acc.w + g0.w) + bb.w, 0.f);
        float s0 = h.x * Wl[(ch4 + 0) * 2] + h.y * Wl[(ch4 + 1) * 2] +
                   h.z * Wl[(ch4 + 2) * 2] + h.w * Wl[(ch4 + 3) * 2];
        float s1 = h.x * Wl[(ch4 + 0) * 2 + 1] + h.y * Wl[(ch4 + 1) * 2 + 1] +
                   h.z * Wl[(ch4 + 2) * 2 + 1] + h.w * Wl[(ch4 + 3) * 2 + 1];
#pragma unroll
        for (int m = 1; m <= 8; m <<= 1) {
            s0 += __shfl_xor(s0, m, 64);
            s1 += __shfl_xor(s1, m, 64);
        }
        if (lane == 0) {
            out[(size_t)wid * 2 + 0] = s0 + bl[0];
            out[(size_t)wid * 2 + 1] = s1 + bl[1];
        }
    }
}

extern "C" void kernel_launch(void* const* d_in, const int* in_sizes, int n_in,
                              void* d_out, int out_size, void* d_ws, size_t ws_size,
                              hipStream_t stream) {
    const float* x  = (const float*)d_in[0];
    const int*   ei = (const int*)d_in[1];
    const float* ew = (const float*)d_in[2];
    const float* W1 = (const float*)d_in[3];
    const float* b1 = (const float*)d_in[4];
    const float* W2 = (const float*)d_in[5];
    const float* b2 = (const float*)d_in[6];
    const float* Wl = (const float*)d_in[7];
    const float* bl = (const float*)d_in[8];
    float* out = (float*)d_out;

    const int N = in_sizes[0] / 16;
    const int E = in_sizes[2];
    const int* row = ei;
    const int* col = ei + E;
    const int NB    = (N + 255) / 256;           // 256 node blocks
    const int nbuck = N >> 8;                    // 256 buckets
    const int chunk = (E + NSB - 1) / NSB;       // 1024 edges per scatter block
    const int FSZ   = nbuck * NSB;               // 256K scan entries
    const int FB    = (FSZ + 255) / 256;         // scanF1 blocks (1024)

    // workspace layout:
    //  R0: pack (E*8 = 8MB)                         [live: s4 -> end]
    //  R1: bufA (N*256 = 16MB)                      [live: s4 gemv tail -> end]
    //  R2: bufB (16MB)  ALIASES {tmp 8MB, F 1MB, bsum 4KB, boff 4KB}
    //      (tmp/F die at s4 end; bufB born at gather_mid)
    //  R3: dinv (256KB), start (256KB+4)
    char* p = (char*)d_ws;
    int2*  pack = (int2*)p;   p += (size_t)E * 8;
    float* bufA = (float*)p;  p += (size_t)N * 64 * 4;
    char*  r2   = p;          p += (size_t)N * 64 * 4;
    float* dinv = (float*)p;  p += (size_t)N * 4;
    int* startO = (int*)p;    p += (size_t)(N + 1) * 4;

    int2* tmp  = (int2*)r2;
    int*  F    = (int*)(r2 + (size_t)E * 8);
    int*  bsum = F + FSZ;
    int*  boff = bsum + FB;
    float* bufB = (float*)r2;

    // ---- CSR build via counting sort (no global atomics) ----
    s1_hist<<<NSB, 256, 0, stream>>>(col, F, E, chunk);
    scanF1<<<FB, 256, 0, stream>>>(F, bsum, FSZ);
    scanF2<<<1, 1024, 0, stream>>>(bsum, boff, FB);
    scanF3<<<FB, 256, 0, stream>>>(F, boff, FSZ);
    s3_scatter<<<NSB, 256, 0, stream>>>(col, row, ew, F, tmp, E, chunk);
    // ---- S4: fine sort + dinv + start + fused layer-1 GEMV (g1 = dinv*(x@W1)) ----
    s4_fine<<<nbuck, 256, 0, stream>>>(tmp, F, pack, dinv, startO, x, W1, bufA, N, E, nbuck);

    // ---- layer 1 aggregate + relu -> h ----
    gather_mid<<<(N + 3) / 4, 256, 0, stream>>>(startO, pack, bufA, dinv, b1, bufB, N);

    // ---- layer 2 GEMM: g2 = dinv*(h@W2) ----
    gemm_hid<<<NB, 256, 0, stream>>>(bufB, W2, dinv, bufA, N);

    // ---- layer 2 aggregate + relu + head -> out ----
    gather_head<<<(N + 3) / 4, 256, 0, stream>>>(startO, pack, bufA, dinv, b2, Wl, bl, out, N);
}

// Round 10
// 138.652 us; speedup vs baseline: 1.4123x; 1.1284x over previous
//
#include <hip/hip_runtime.h>
#include <hip/hip_fp16.h>

#define NSB 1024                          // scatter blocks (edge chunks)

__device__ __forceinline__ unsigned pack_h2(float a, float b) {
    __half2 h = __floats2half2_rn(a, b);
    return *reinterpret_cast<unsigned*>(&h);
}

// ---------------- S1: per-(block,bucket) histogram of col>>8, no global atomics ----------
__global__ __launch_bounds__(256) void s1_hist(const int* __restrict__ col,
                                               int* __restrict__ F, int E, int chunk) {
    __shared__ int cnt[256];
    int t = threadIdx.x, b = blockIdx.x;
    cnt[t] = 0;
    __syncthreads();
    int s = b * chunk, e = min(E, s + chunk);
    for (int i = s + t; i < e; i += 256) atomicAdd(&cnt[col[i] >> 8], 1);   // LDS atomic
    __syncthreads();
    F[t * NSB + b] = cnt[t];              // bucket-major: F[bucket*NSB + block]
}

// ---------------- scan of F (256K entries): 3 stages ----------------
__global__ void scanF1(int* __restrict__ F, int* __restrict__ bsum, int n) {
    __shared__ int sd[256];
    int t = threadIdx.x, i = blockIdx.x * 256 + t;
    int v = (i < n) ? F[i] : 0;
    sd[t] = v;
    __syncthreads();
    for (int o = 1; o < 256; o <<= 1) {
        int x = (t >= o) ? sd[t - o] : 0;
        __syncthreads();
        sd[t] += x;
        __syncthreads();
    }
    if (i < n) F[i] = sd[t] - v;          // local exclusive, in place
    if (t == 255) bsum[blockIdx.x] = sd[255];
}

__global__ void scanF2(const int* __restrict__ bsum, int* __restrict__ boff, int nb) {
    __shared__ int sd[1024];
    int t = threadIdx.x;
    int v = (t < nb) ? bsum[t] : 0;
    sd[t] = v;
    __syncthreads();
    for (int o = 1; o < 1024; o <<= 1) {
        int x = (t >= o) ? sd[t - o] : 0;
        __syncthreads();
        sd[t] += x;
        __syncthreads();
    }
    if (t < nb) boff[t] = sd[t] - v;
}

__global__ void scanF3(int* __restrict__ F, const int* __restrict__ boff, int n) {
    int i = blockIdx.x * blockDim.x + threadIdx.x;
    if (i < n) F[i] += boff[i >> 8];
}

// ---------------- S3: scatter edges into bucket-grouped tmp (LDS rank atomics only) -----
// tmp[pos] = (row | fine<<16, ew_bits_fp32)
__global__ __launch_bounds__(256) void s3_scatter(const int* __restrict__ col,
                                                  const int* __restrict__ row,
                                                  const float* __restrict__ ew,
                                                  const int* __restrict__ F,
                                                  int2* __restrict__ tmp, int E, int chunk) {
    __shared__ int off[256];
    __shared__ int cur[256];
    int t = threadIdx.x, b = blockIdx.x;
    off[t] = F[t * NSB + b];
    cur[t] = 0;
    __syncthreads();
    int s = b * chunk, e = min(E, s + chunk);
    for (int i = s + t; i < e; i += 256) {
        int c = col[i];
        int bk = c >> 8;
        int rk = atomicAdd(&cur[bk], 1);  // LDS returning atomic (cheap)
        tmp[off[bk] + rk] = make_int2(row[i] | ((c & 255) << 16), __float_as_int(ew[i]));
    }
}

// ---------------- S4: per-bucket fine sort -> pack/start/dinv + fused layer-1 GEMV ------
// block b owns bucket b (nodes b*256..+255); thread t owns node c = b*256+t.
// final pack entry = row(16b) | half(ew)(16b);  g1 = dinv * (x @ W1)  in fp16
__global__ __launch_bounds__(256) void s4_fine(const int2* __restrict__ tmp,
                                               const int* __restrict__ F,
                                               unsigned* __restrict__ pack,
                                               float* __restrict__ dinv,
                                               int* __restrict__ start,
                                               const float* __restrict__ x,
                                               const float* __restrict__ W1,
                                               __half* __restrict__ g1,
                                               int n, int E, int nbuck) {
    __shared__ int   fcnt[256];
    __shared__ float fdeg[256];
    __shared__ int   foff[256];
    __shared__ int   fcur[256];
    __shared__ float Ws[16 * 64];
    int t = threadIdx.x, b = blockIdx.x;
    reinterpret_cast<float4*>(Ws)[t] = reinterpret_cast<const float4*>(W1)[t];  // 4KB
    fcnt[t] = 0; fdeg[t] = 0.f; fcur[t] = 0;
    __syncthreads();
    int segS = F[b * NSB];
    int segE = (b == nbuck - 1) ? E : F[(b + 1) * NSB];
    for (int i = segS + t; i < segE; i += 256) {
        int2 v = tmp[i];
        int f = (v.x >> 16) & 255;
        atomicAdd(&fcnt[f], 1);
        atomicAdd(&fdeg[f], __int_as_float(v.y));   // LDS float atomic (fp32 degree)
    }
    __syncthreads();
    int val = fcnt[t];
    foff[t] = val;
    __syncthreads();
    for (int o = 1; o < 256; o <<= 1) {             // Hillis-Steele inclusive
        int xk = (t >= o) ? foff[t - o] : 0;
        __syncthreads();
        foff[t] += xk;
        __syncthreads();
    }
    int excl = foff[t] - val;
    int c = (b << 8) | t;
    float di = rsqrtf(fdeg[t] + 1.0f);              // + self-loop; deg>=1 always
    if (c < n) {
        dinv[c]  = di;
        start[c] = segS + excl;
    }
    if (b == nbuck - 1 && t == 255) start[n] = E;
    __syncthreads();
    foff[t] = excl;
    __syncthreads();
    for (int i = segS + t; i < segE; i += 256) {    // scatter to final CSR slots
        int2 v = tmp[i];
        int f = (v.x >> 16) & 255;
        int rk = atomicAdd(&fcur[f], 1);
        __half hw = __float2half_rn(__int_as_float(v.y));
        pack[segS + foff[f] + rk] =
            (unsigned)(v.x & 0xFFFF) | ((unsigned)*reinterpret_cast<unsigned short*>(&hw) << 16);
    }
    // ---- fused layer-1 GEMV: g1[c] = di * (x[c,:16] @ W1), fp16 out ----
    if (c >= n) return;
    float xv[16];
    const float4* xr = reinterpret_cast<const float4*>(x + (size_t)c * 16);
#pragma unroll
    for (int i = 0; i < 4; ++i)
        *reinterpret_cast<float4*>(&xv[i * 4]) = xr[i];
    uint2* orow = reinterpret_cast<uint2*>(g1 + ((size_t)c << 6));
    for (int jb = 0; jb < 16; ++jb) {
        float4 acc = make_float4(0.f, 0.f, 0.f, 0.f);
#pragma unroll
        for (int k = 0; k < 16; ++k) {
            float hk = xv[k];
            const float4 wv = *reinterpret_cast<const float4*>(&Ws[k * 64 + jb * 4]);
            acc.x += hk * wv.x; acc.y += hk * wv.y;
            acc.z += hk * wv.z; acc.w += hk * wv.w;
        }
        uint2 st;
        st.x = pack_h2(acc.x * di, acc.y * di);
        st.y = pack_h2(acc.z * di, acc.w * di);
        orow[jb] = st;
    }
}

// ---------------- dense: h[N,64] @ W[64,64] -> g2 = dinv*(h@W2) in fp16 ----------------
__global__ __launch_bounds__(256) void gemm_hid(const float* __restrict__ h,
                                                const float* __restrict__ W,
                                                const float* __restrict__ dinv,
                                                __half* __restrict__ out, int n) {
    __shared__ float Ws[64 * 64];
    int t = threadIdx.x;
#pragma unroll
    for (int i = 0; i < 16; ++i) Ws[i * 256 + t] = W[i * 256 + t];
    __syncthreads();
    int node = blockIdx.x * 256 + t;
    if (node >= n) return;
    float hv[64];
    const float4* hr = reinterpret_cast<const float4*>(h + ((size_t)node << 6));
#pragma unroll
    for (int i = 0; i < 16; ++i)
        *reinterpret_cast<float4*>(&hv[i * 4]) = hr[i];
    float di = dinv[node];
    uint2* orow = reinterpret_cast<uint2*>(out + ((size_t)node << 6));
    for (int jb = 0; jb < 16; ++jb) {
        float4 acc = make_float4(0.f, 0.f, 0.f, 0.f);
#pragma unroll
        for (int k = 0; k < 64; ++k) {
            float hk = hv[k];
            const float4 wv = *reinterpret_cast<const float4*>(&Ws[k * 64 + jb * 4]);
            acc.x += hk * wv.x; acc.y += hk * wv.y;
            acc.z += hk * wv.z; acc.w += hk * wv.w;
        }
        uint2 st;
        st.x = pack_h2(acc.x * di, acc.y * di);
        st.y = pack_h2(acc.z * di, acc.w * di);
        orow[jb] = st;
    }
}

// ---------------- shared gather body: 4 subs x 4 fp16 ch (8B loads), 8 edges in flight ---
__device__ __forceinline__ float4 load_row4(const __half* __restrict__ g,
                                            unsigned pk, int ch4, float* wout) {
    unsigned short hw = (unsigned short)(pk >> 16);
    *wout = __half2float(*reinterpret_cast<__half*>(&hw));
    uint2 u = *reinterpret_cast<const uint2*>(g + ((size_t)(pk & 0xFFFFu) << 6) + ch4);
    float2 a = __half22float2(*reinterpret_cast<__half2*>(&u.x));
    float2 b = __half22float2(*reinterpret_cast<__half2*>(&u.y));
    return make_float4(a.x, a.y, b.x, b.y);
}

__device__ __forceinline__ float4 gather_acc(const int* __restrict__ start,
                                             const unsigned* __restrict__ pack,
                                             const __half* __restrict__ g,
                                             int wid, int sub, int ch4) {
    int s = start[wid], e = start[wid + 1];
    float4 acc = make_float4(0.f, 0.f, 0.f, 0.f);
    int i = s;
    for (; i + 7 < e; i += 8) {                 // 8 edges in flight per wave
        unsigned pa = pack[i + sub];
        unsigned pb = pack[i + 4 + sub];
        float wa, wb;
        float4 va = load_row4(g, pa, ch4, &wa);
        float4 vb = load_row4(g, pb, ch4, &wb);
        acc.x += va.x * wa; acc.y += va.y * wa; acc.z += va.z * wa; acc.w += va.w * wa;
        acc.x += vb.x * wb; acc.y += vb.y * wb; acc.z += vb.z * wb; acc.w += vb.w * wb;
    }
    if (i + 3 < e) {
        unsigned pa = pack[i + sub];
        float wa;
        float4 va = load_row4(g, pa, ch4, &wa);
        acc.x += va.x * wa; acc.y += va.y * wa; acc.z += va.z * wa; acc.w += va.w * wa;
        i += 4;
    }
    int rem = e - i;
    if (sub < rem) {
        unsigned pa = pack[i + sub];
        float wa;
        float4 va = load_row4(g, pa, ch4, &wa);
        acc.x += va.x * wa; acc.y += va.y * wa; acc.z += va.z * wa; acc.w += va.w * wa;
    }
#pragma unroll
    for (int m = 16; m <= 32; m <<= 1) {        // reduce across 4 sub groups
        acc.x += __shfl_xor(acc.x, m, 64);
        acc.y += __shfl_xor(acc.y, m, 64);
        acc.z += __shfl_xor(acc.z, m, 64);
        acc.w += __shfl_xor(acc.w, m, 64);
    }
    return acc;
}

// ---------------- gather (mid layer): h_out = relu(di*(acc + g[c]) + b), fp32 out -------
__global__ __launch_bounds__(256) void gather_mid(const int* __restrict__ start,
                                                  const unsigned* __restrict__ pack,
                                                  const __half* __restrict__ g,
                                                  const float* __restrict__ dinv,
                                                  const float* __restrict__ b,
                                                  float* __restrict__ out, int n) {
    int wid = (blockIdx.x * blockDim.x + threadIdx.x) >> 6;
    if (wid >= n) return;
    int lane = threadIdx.x & 63;
    int sub = lane >> 4;
    int ch4 = (lane & 15) << 2;
    float4 acc = gather_acc(start, pack, g, wid, sub, ch4);
    if (sub == 0) {                              // lanes 0..15 write 256B contiguous
        float di = dinv[wid];
        uint2 u0 = *reinterpret_cast<const uint2*>(g + ((size_t)wid << 6) + ch4);
        float2 ga = __half22float2(*reinterpret_cast<__half2*>(&u0.x));
        float2 gb = __half22float2(*reinterpret_cast<__half2*>(&u0.y));
        const float4 bb = *reinterpret_cast<const float4*>(b + ch4);
        float4 r;
        r.x = fmaxf(di * (acc.x + ga.x) + bb.x, 0.f);
        r.y = fmaxf(di * (acc.y + ga.y) + bb.y, 0.f);
        r.z = fmaxf(di * (acc.z + gb.x) + bb.z, 0.f);
        r.w = fmaxf(di * (acc.w + gb.y) + bb.w, 0.f);
        *reinterpret_cast<float4*>(out + ((size_t)wid << 6) + ch4) = r;
    }
}

// ---------------- gather (final layer) + head fused: out[c,0:2] ----------------
__global__ __launch_bounds__(256) void gather_head(const int* __restrict__ start,
                                                   const unsigned* __restrict__ pack,
                                                   const __half* __restrict__ g,
                                                   const float* __restrict__ dinv,
                                                   const float* __restrict__ b,
                                                   const float* __restrict__ Wl,
                                                   const float* __restrict__ bl,
                                                   float* __restrict__ out, int n) {
    int wid = (blockIdx.x * blockDim.x + threadIdx.x) >> 6;
    if (wid >= n) return;
    int lane = threadIdx.x & 63;
    int sub = lane >> 4;
    int ch4 = (lane & 15) << 2;
    float4 acc = gather_acc(start, pack, g, wid, sub, ch4);
    if (sub == 0) {
        float di = dinv[wid];
        uint2 u0 = *reinterpret_cast<const uint2*>(g + ((size_t)wid << 6) + ch4);
        float2 ga = __half22float2(*reinterpret_cast<__half2*>(&u0.x));
        float2 gb = __half22float2(*reinterpret_cast<__half2*>(&u0.y));
        const float4 bb = *reinterpret_cast<const float4*>(b + ch4);
        float4 h;
        h.x = fmaxf(di * (acc.x + ga.x) + bb.x, 0.f);
        h.y = fmaxf(di * (acc.y + ga.y) + bb.y, 0.f);
        h.z = fmaxf(di * (acc.z + gb.x) + bb.z, 0.f);
        h.w = fmaxf(di * (acc.w + gb.y) + bb.w, 0.f);
        float s0 = h.x * Wl[(ch4 + 0) * 2] + h.y * Wl[(ch4 + 1) * 2] +
                   h.z * Wl[(ch4 + 2) * 2] + h.w * Wl[(ch4 + 3) * 2];
        float s1 = h.x * Wl[(ch4 + 0) * 2 + 1] + h.y * Wl[(ch4 + 1) * 2 + 1] +
                   h.z * Wl[(ch4 + 2) * 2 + 1] + h.w * Wl[(ch4 + 3) * 2 + 1];
#pragma unroll
        for (int m = 1; m <= 8; m <<= 1) {       // reduce across lanes 0..15
            s0 += __shfl_xor(s0, m, 64);
            s1 += __shfl_xor(s1, m, 64);
        }
        if (lane == 0) {
            out[(size_t)wid * 2 + 0] = s0 + bl[0];
            out[(size_t)wid * 2 + 1] = s1 + bl[1];
        }
    }
}

extern "C" void kernel_launch(void* const* d_in, const int* in_sizes, int n_in,
                              void* d_out, int out_size, void* d_ws, size_t ws_size,
                              hipStream_t stream) {
    const float* x  = (const float*)d_in[0];
    const int*   ei = (const int*)d_in[1];
    const float* ew = (const float*)d_in[2];
    const float* W1 = (const float*)d_in[3];
    const float* b1 = (const float*)d_in[4];
    const float* W2 = (const float*)d_in[5];
    const float* b2 = (const float*)d_in[6];
    const float* Wl = (const float*)d_in[7];
    const float* bl = (const float*)d_in[8];
    float* out = (float*)d_out;

    const int N = in_sizes[0] / 16;
    const int E = in_sizes[2];
    const int* row = ei;
    const int* col = ei + E;
    const int NB    = (N + 255) / 256;           // 256 node blocks
    const int nbuck = N >> 8;                    // 256 buckets
    const int chunk = (E + NSB - 1) / NSB;       // 1024 edges per scatter block
    const int FSZ   = nbuck * NSB;               // 256K scan entries
    const int FB    = (FSZ + 255) / 256;         // scanF1 blocks (1024)

    // workspace layout:
    //  R0: pack (E*4 = 4MB)                 [live: s4 -> end]
    //  R1: bufA = g (N*64*2 = 8MB fp16)     [live: s4 gemv tail -> end]
    //  R2: 16MB region: bufB (h, fp32) ALIASES {tmp 8MB, F 1MB, bsum, boff}
    //  R3: dinv (256KB), start (256KB+4)
    char* p = (char*)d_ws;
    unsigned* pack = (unsigned*)p;  p += (size_t)E * 4;
    __half*   bufA = (__half*)p;    p += (size_t)N * 64 * 2;
    char*     r2   = p;             p += (size_t)N * 64 * 4;
    float*    dinv = (float*)p;     p += (size_t)N * 4;
    int*    startO = (int*)p;       p += (size_t)(N + 1) * 4;

    int2* tmp  = (int2*)r2;
    int*  F    = (int*)(r2 + (size_t)E * 8);
    int*  bsum = F + FSZ;
    int*  boff = bsum + FB;
    float* bufB = (float*)r2;

    // ---- CSR build via counting sort (no global atomics) ----
    s1_hist<<<NSB, 256, 0, stream>>>(col, F, E, chunk);
    scanF1<<<FB, 256, 0, stream>>>(F, bsum, FSZ);
    scanF2<<<1, 1024, 0, stream>>>(bsum, boff, FB);
    scanF3<<<FB, 256, 0, stream>>>(F, boff, FSZ);
    s3_scatter<<<NSB, 256, 0, stream>>>(col, row, ew, F, tmp, E, chunk);
    // ---- S4: fine sort + dinv + start + fused layer-1 GEMV (g1 = dinv*(x@W1), fp16) ----
    s4_fine<<<nbuck, 256, 0, stream>>>(tmp, F, pack, dinv, startO, x, W1, bufA, N, E, nbuck);

    // ---- layer 1 aggregate + relu -> h (fp32) ----
    gather_mid<<<(N + 3) / 4, 256, 0, stream>>>(startO, pack, bufA, dinv, b1, bufB, N);

    // ---- layer 2 GEMM: g2 = dinv*(h@W2) (fp16) ----
    gemm_hid<<<NB, 256, 0, stream>>>(bufB, W2, dinv, bufA, N);

    // ---- layer 2 aggregate + relu + head -> out ----
    gather_head<<<(N + 3) / 4, 256, 0, stream>>>(startO, pack, bufA, dinv, b2, Wl, bl, out, N);
}

// Round 11
// 137.882 us; speedup vs baseline: 1.4202x; 1.0056x over previous
//
#include <hip/hip_runtime.h>
#include <hip/hip_fp16.h>

#define CHUNK 4096                        // edges per s1/s3 block
#define SEGCAP 6144                       // s4 LDS segment capacity (mean 4096 + 32 sigma)

__device__ __forceinline__ unsigned pack_h2(float a, float b) {
    __half2 h = __floats2half2_rn(a, b);
    return *reinterpret_cast<unsigned*>(&h);
}

// exclusive-scan bsum[nb<=256] into boff[256] (LDS), all 256 threads participate
__device__ __forceinline__ void scan_boff(const int* __restrict__ bsum, int nb,
                                          int* boff) {
    int t = threadIdx.x;
    int v = (t < nb) ? bsum[t] : 0;
    boff[t] = v;
    __syncthreads();
    for (int o = 1; o < 256; o <<= 1) {
        int x = (t >= o) ? boff[t - o] : 0;
        __syncthreads();
        boff[t] += x;
        __syncthreads();
    }
    int excl = boff[t] - v;
    __syncthreads();
    boff[t] = excl;
    __syncthreads();
}

// ---------------- S1: per-(block,bucket) histogram of col>>8 ----------------
__global__ __launch_bounds__(256) void s1_hist(const int* __restrict__ col,
                                               int* __restrict__ F, int E, int nsb) {
    __shared__ int cnt[256];
    int t = threadIdx.x, b = blockIdx.x;
    cnt[t] = 0;
    __syncthreads();
    int s = b * CHUNK, e = min(E, s + CHUNK);
    for (int i = s + t; i < e; i += 256) atomicAdd(&cnt[col[i] >> 8], 1);   // LDS atomic
    __syncthreads();
    F[t * nsb + b] = cnt[t];              // bucket-major: F[bucket*nsb + block]
}

// ---------------- scanF1: local exclusive scan of F (in place) + bsum ----------------
__global__ void scanF1(int* __restrict__ F, int* __restrict__ bsum, int n) {
    __shared__ int sd[256];
    int t = threadIdx.x, i = blockIdx.x * 256 + t;
    int v = (i < n) ? F[i] : 0;
    sd[t] = v;
    __syncthreads();
    for (int o = 1; o < 256; o <<= 1) {
        int x = (t >= o) ? sd[t - o] : 0;
        __syncthreads();
        sd[t] += x;
        __syncthreads();
    }
    if (i < n) F[i] = sd[t] - v;
    if (t == 255) bsum[blockIdx.x] = sd[255];
}

// ---------------- S3: block-local counting sort -> coalesced scatter to tmp -------------
// tmp[pos] = (row(16b) | c(16b)<<16, ew_fp32). Requires nsb == 256 (E fixed at 1M).
__global__ __launch_bounds__(256) void s3_scatter(const int* __restrict__ col,
                                                  const int* __restrict__ row,
                                                  const float* __restrict__ ew,
                                                  const int* __restrict__ F,
                                                  const int* __restrict__ bsum,
                                                  int2* __restrict__ tmp, int E, int nsb) {
    __shared__ int boff[256];
    __shared__ int off[256];
    __shared__ int cnt[256];
    __shared__ int lofs[256];
    __shared__ int cur[256];
    __shared__ int2 ed[CHUNK];                 // 32KB staged edges
    __shared__ unsigned short perm[CHUNK];     // 8KB dest-order permutation
    int t = threadIdx.x, b = blockIdx.x;
    scan_boff(bsum, nsb, boff);                // boff = exclusive scan of block sums
    // linear F idx = t*nsb + b ; scanF1 block = idx>>8 = t (nsb==256)
    off[t] = F[t * nsb + b] + boff[t];
    cnt[t] = 0; cur[t] = 0;
    __syncthreads();
    int s = b * CHUNK;
    int m = min(E - s, CHUNK);
    // pass 1: stage + bucket counts
    for (int i = t; i < m; i += 256) {
        int c = col[s + i];
        ed[i] = make_int2((row[s + i] & 0xFFFF) | (c << 16), __float_as_int(ew[s + i]));
        atomicAdd(&cnt[c >> 8], 1);
    }
    __syncthreads();
    // local exclusive scan of cnt -> lofs
    int v = cnt[t];
    lofs[t] = v;
    __syncthreads();
    for (int o = 1; o < 256; o <<= 1) {
        int x = (t >= o) ? lofs[t - o] : 0;
        __syncthreads();
        lofs[t] += x;
        __syncthreads();
    }
    int excl = lofs[t] - v;
    __syncthreads();
    lofs[t] = excl;
    __syncthreads();
    // pass 2: build permutation (any within-bucket order is valid)
    for (int i = t; i < m; i += 256) {
        int bk = ((unsigned)ed[i].x) >> 24;
        int rk = atomicAdd(&cur[bk], 1);
        perm[lofs[bk] + rk] = (unsigned short)i;
    }
    __syncthreads();
    // pass 3: write in destination order -> coalesced global stores
    for (int p = t; p < m; p += 256) {
        int2 v2 = ed[perm[p]];
        int bk = ((unsigned)v2.x) >> 24;
        tmp[off[bk] + (p - lofs[bk])] = v2;
    }
}

// ---------------- S4: per-bucket fine sort (LDS-resident) + dinv/start + L1 GEMV --------
// block b owns bucket b (nodes b*256..+255); thread t owns node c = b*256+t.
// pack entry = row(16b) | half(ew)(16b);  g1 = dinv * (x @ W1) in fp16
__global__ __launch_bounds__(256) void s4_fine(const int2* __restrict__ tmp,
                                               const int* __restrict__ F,
                                               const int* __restrict__ bsum,
                                               unsigned* __restrict__ pack,
                                               float* __restrict__ dinv,
                                               int* __restrict__ start,
                                               const float* __restrict__ x,
                                               const float* __restrict__ W1,
                                               __half* __restrict__ g1,
                                               int n, int E, int nsb, int nbuck) {
    __shared__ int   boff[256];
    __shared__ int   fcnt[256];
    __shared__ float fdeg[256];
    __shared__ int   foff[256];
    __shared__ int   fcur[256];
    __shared__ float Ws[16 * 64];
    __shared__ int2  seg[SEGCAP];              // 48KB
    __shared__ unsigned short perm[SEGCAP];    // 12KB
    int t = threadIdx.x, b = blockIdx.x;
    scan_boff(bsum, nsb, boff);
    reinterpret_cast<float4*>(Ws)[t] = reinterpret_cast<const float4*>(W1)[t];  // 4KB
    fcnt[t] = 0; fdeg[t] = 0.f; fcur[t] = 0;
    __syncthreads();
    int segS = F[b * nsb] + boff[b];                       // linear idx b*nsb -> block b
    int segE = (b == nbuck - 1) ? E : (F[(b + 1) * nsb] + boff[b + 1]);
    int m = segE - segS;
    if (m <= SEGCAP) {
        for (int i = t; i < m; i += 256) seg[i] = tmp[segS + i];   // coalesced stage
        __syncthreads();
        for (int i = t; i < m; i += 256) {
            int2 v = seg[i];
            int f = (v.x >> 16) & 255;
            atomicAdd(&fcnt[f], 1);
            atomicAdd(&fdeg[f], __int_as_float(v.y));      // LDS float atomic (fp32)
        }
        __syncthreads();
        int val = fcnt[t];
        foff[t] = val;
        __syncthreads();
        for (int o = 1; o < 256; o <<= 1) {
            int xk = (t >= o) ? foff[t - o] : 0;
            __syncthreads();
            foff[t] += xk;
            __syncthreads();
        }
        int excl = foff[t] - val;
        __syncthreads();
        foff[t] = excl;
        __syncthreads();
        for (int i = t; i < m; i += 256) {                 // permutation
            int f = (seg[i].x >> 16) & 255;
            int rk = atomicAdd(&fcur[f], 1);
            perm[foff[f] + rk] = (unsigned short)i;
        }
        __syncthreads();
        for (int p = t; p < m; p += 256) {                 // coalesced pack write
            int2 v = seg[perm[p]];
            __half hw = __float2half_rn(__int_as_float(v.y));
            pack[segS + p] = (unsigned)(v.x & 0xFFFF) |
                             ((unsigned)*reinterpret_cast<unsigned short*>(&hw) << 16);
        }
    } else {
        // fallback: 2-pass global (pathological bucket)
        for (int i = segS + t; i < segE; i += 256) {
            int2 v = tmp[i];
            int f = (v.x >> 16) & 255;
            atomicAdd(&fcnt[f], 1);
            atomicAdd(&fdeg[f], __int_as_float(v.y));
        }
        __syncthreads();
        int val = fcnt[t];
        foff[t] = val;
        __syncthreads();
        for (int o = 1; o < 256; o <<= 1) {
            int xk = (t >= o) ? foff[t - o] : 0;
            __syncthreads();
            foff[t] += xk;
            __syncthreads();
        }
        int excl = foff[t] - val;
        __syncthreads();
        foff[t] = excl;
        __syncthreads();
        for (int i = segS + t; i < segE; i += 256) {
            int2 v = tmp[i];
            int f = (v.x >> 16) & 255;
            int rk = atomicAdd(&fcur[f], 1);
            __half hw = __float2half_rn(__int_as_float(v.y));
            pack[segS + foff[f] + rk] = (unsigned)(v.x & 0xFFFF) |
                             ((unsigned)*reinterpret_cast<unsigned short*>(&hw) << 16);
        }
    }
    int c = (b << 8) | t;
    float di = rsqrtf(fdeg[t] + 1.0f);              // + self-loop; deg>=1 always
    if (c < n) {
        dinv[c]  = di;
        start[c] = segS + foff[t];
    }
    if (b == nbuck - 1 && t == 255) start[n] = E;
    // ---- fused layer-1 GEMV: g1[c] = di * (x[c,:16] @ W1), fp16 out ----
    if (c >= n) return;
    float xv[16];
    const float4* xr = reinterpret_cast<const float4*>(x + (size_t)c * 16);
#pragma unroll
    for (int i = 0; i < 4; ++i)
        *reinterpret_cast<float4*>(&xv[i * 4]) = xr[i];
    uint2* orow = reinterpret_cast<uint2*>(g1 + ((size_t)c << 6));
    for (int jb = 0; jb < 16; ++jb) {
        float4 acc = make_float4(0.f, 0.f, 0.f, 0.f);
#pragma unroll
        for (int k = 0; k < 16; ++k) {
            float hk = xv[k];
            const float4 wv = *reinterpret_cast<const float4*>(&Ws[k * 64 + jb * 4]);
            acc.x += hk * wv.x; acc.y += hk * wv.y;
            acc.z += hk * wv.z; acc.w += hk * wv.w;
        }
        uint2 st;
        st.x = pack_h2(acc.x * di, acc.y * di);
        st.y = pack_h2(acc.z * di, acc.w * di);
        orow[jb] = st;
    }
}

// ---------------- dense: h[N,64] @ W[64,64] -> g2 = dinv*(h@W2) in fp16 ----------------
__global__ __launch_bounds__(256) void gemm_hid(const float* __restrict__ h,
                                                const float* __restrict__ W,
                                                const float* __restrict__ dinv,
                                                __half* __restrict__ out, int n) {
    __shared__ float Ws[64 * 64];
    int t = threadIdx.x;
#pragma unroll
    for (int i = 0; i < 16; ++i) Ws[i * 256 + t] = W[i * 256 + t];
    __syncthreads();
    int node = blockIdx.x * 256 + t;
    if (node >= n) return;
    float hv[64];
    const float4* hr = reinterpret_cast<const float4*>(h + ((size_t)node << 6));
#pragma unroll
    for (int i = 0; i < 16; ++i)
        *reinterpret_cast<float4*>(&hv[i * 4]) = hr[i];
    float di = dinv[node];
    uint2* orow = reinterpret_cast<uint2*>(out + ((size_t)node << 6));
    for (int jb = 0; jb < 16; ++jb) {
        float4 acc = make_float4(0.f, 0.f, 0.f, 0.f);
#pragma unroll
        for (int k = 0; k < 64; ++k) {
            float hk = hv[k];
            const float4 wv = *reinterpret_cast<const float4*>(&Ws[k * 64 + jb * 4]);
            acc.x += hk * wv.x; acc.y += hk * wv.y;
            acc.z += hk * wv.z; acc.w += hk * wv.w;
        }
        uint2 st;
        st.x = pack_h2(acc.x * di, acc.y * di);
        st.y = pack_h2(acc.z * di, acc.w * di);
        orow[jb] = st;
    }
}

// ---------------- shared gather body: 4 subs x 4 fp16 ch (8B loads), 8 edges in flight ---
__device__ __forceinline__ float4 load_row4(const __half* __restrict__ g,
                                            unsigned pk, int ch4, float* wout) {
    unsigned short hw = (unsigned short)(pk >> 16);
    *wout = __half2float(*reinterpret_cast<__half*>(&hw));
    uint2 u = *reinterpret_cast<const uint2*>(g + ((size_t)(pk & 0xFFFFu) << 6) + ch4);
    float2 a = __half22float2(*reinterpret_cast<__half2*>(&u.x));
    float2 b = __half22float2(*reinterpret_cast<__half2*>(&u.y));
    return make_float4(a.x, a.y, b.x, b.y);
}

__device__ __forceinline__ float4 gather_acc(const int* __restrict__ start,
                                             const unsigned* __restrict__ pack,
                                             const __half* __restrict__ g,
                                             int wid, int sub, int ch4) {
    int s = start[wid], e = start[wid + 1];
    float4 acc = make_float4(0.f, 0.f, 0.f, 0.f);
    int i = s;
    for (; i + 7 < e; i += 8) {                 // 8 edges in flight per wave
        unsigned pa = pack[i + sub];
        unsigned pb = pack[i + 4 + sub];
        float wa, wb;
        float4 va = load_row4(g, pa, ch4, &wa);
        float4 vb = load_row4(g, pb, ch4, &wb);
        acc.x += va.x * wa; acc.y += va.y * wa; acc.z += va.z * wa; acc.w += va.w * wa;
        acc.x += vb.x * wb; acc.y += vb.y * wb; acc.z += vb.z * wb; acc.w += vb.w * wb;
    }
    if (i + 3 < e) {
        unsigned pa = pack[i + sub];
        float wa;
        float4 va = load_row4(g, pa, ch4, &wa);
        acc.x += va.x * wa; acc.y += va.y * wa; acc.z += va.z * wa; acc.w += va.w * wa;
        i += 4;
    }
    int rem = e - i;
    if (sub < rem) {
        unsigned pa = pack[i + sub];
        float wa;
        float4 va = load_row4(g, pa, ch4, &wa);
        acc.x += va.x * wa; acc.y += va.y * wa; acc.z += va.z * wa; acc.w += va.w * wa;
    }
#pragma unroll
    for (int m = 16; m <= 32; m <<= 1) {        // reduce across 4 sub groups
        acc.x += __shfl_xor(acc.x, m, 64);
        acc.y += __shfl_xor(acc.y, m, 64);
        acc.z += __shfl_xor(acc.z, m, 64);
        acc.w += __shfl_xor(acc.w, m, 64);
    }
    return acc;
}

// ---------------- gather (mid layer): h_out = relu(di*(acc + g[c]) + b), fp32 out -------
__global__ __launch_bounds__(256) void gather_mid(const int* __restrict__ start,
                                                  const unsigned* __restrict__ pack,
                                                  const __half* __restrict__ g,
                                                  const float* __restrict__ dinv,
                                                  const float* __restrict__ b,
                                                  float* __restrict__ out, int n) {
    int wid = (blockIdx.x * blockDim.x + threadIdx.x) >> 6;
    if (wid >= n) return;
    int lane = threadIdx.x & 63;
    int sub = lane >> 4;
    int ch4 = (lane & 15) << 2;
    float4 acc = gather_acc(start, pack, g, wid, sub, ch4);
    if (sub == 0) {                              // lanes 0..15 write 256B contiguous
        float di = dinv[wid];
        uint2 u0 = *reinterpret_cast<const uint2*>(g + ((size_t)wid << 6) + ch4);
        float2 ga = __half22float2(*reinterpret_cast<__half2*>(&u0.x));
        float2 gb = __half22float2(*reinterpret_cast<__half2*>(&u0.y));
        const float4 bb = *reinterpret_cast<const float4*>(b + ch4);
        float4 r;
        r.x = fmaxf(di * (acc.x + ga.x) + bb.x, 0.f);
        r.y = fmaxf(di * (acc.y + ga.y) + bb.y, 0.f);
        r.z = fmaxf(di * (acc.z + gb.x) + bb.z, 0.f);
        r.w = fmaxf(di * (acc.w + gb.y) + bb.w, 0.f);
        *reinterpret_cast<float4*>(out + ((size_t)wid << 6) + ch4) = r;
    }
}

// ---------------- gather (final layer) + head fused: out[c,0:2] ----------------
__global__ __launch_bounds__(256) void gather_head(const int* __restrict__ start,
                                                   const unsigned* __restrict__ pack,
                                                   const __half* __restrict__ g,
                                                   const float* __restrict__ dinv,
                                                   const float* __restrict__ b,
                                                   const float* __restrict__ Wl,
                                                   const float* __restrict__ bl,
                                                   float* __restrict__ out, int n) {
    int wid = (blockIdx.x * blockDim.x + threadIdx.x) >> 6;
    if (wid >= n) return;
    int lane = threadIdx.x & 63;
    int sub = lane >> 4;
    int ch4 = (lane & 15) << 2;
    float4 acc = gather_acc(start, pack, g, wid, sub, ch4);
    if (sub == 0) {
        float di = dinv[wid];
        uint2 u0 = *reinterpret_cast<const uint2*>(g + ((size_t)wid << 6) + ch4);
        float2 ga = __half22float2(*reinterpret_cast<__half2*>(&u0.x));
        float2 gb = __half22float2(*reinterpret_cast<__half2*>(&u0.y));
        const float4 bb = *reinterpret_cast<const float4*>(b + ch4);
        float4 h;
        h.x = fmaxf(di * (acc.x + ga.x) + bb.x, 0.f);
        h.y = fmaxf(di * (acc.y + ga.y) + bb.y, 0.f);
        h.z = fmaxf(di * (acc.z + gb.x) + bb.z, 0.f);
        h.w = fmaxf(di * (acc.w + gb.y) + bb.w, 0.f);
        float s0 = h.x * Wl[(ch4 + 0) * 2] + h.y * Wl[(ch4 + 1) * 2] +
                   h.z * Wl[(ch4 + 2) * 2] + h.w * Wl[(ch4 + 3) * 2];
        float s1 = h.x * Wl[(ch4 + 0) * 2 + 1] + h.y * Wl[(ch4 + 1) * 2 + 1] +
                   h.z * Wl[(ch4 + 2) * 2 + 1] + h.w * Wl[(ch4 + 3) * 2 + 1];
#pragma unroll
        for (int m = 1; m <= 8; m <<= 1) {       // reduce across lanes 0..15
            s0 += __shfl_xor(s0, m, 64);
            s1 += __shfl_xor(s1, m, 64);
        }
        if (lane == 0) {
            out[(size_t)wid * 2 + 0] = s0 + bl[0];
            out[(size_t)wid * 2 + 1] = s1 + bl[1];
        }
    }
}

extern "C" void kernel_launch(void* const* d_in, const int* in_sizes, int n_in,
                              void* d_out, int out_size, void* d_ws, size_t ws_size,
                              hipStream_t stream) {
    const float* x  = (const float*)d_in[0];
    const int*   ei = (const int*)d_in[1];
    const float* ew = (const float*)d_in[2];
    const float* W1 = (const float*)d_in[3];
    const float* b1 = (const float*)d_in[4];
    const float* W2 = (const float*)d_in[5];
    const float* b2 = (const float*)d_in[6];
    const float* Wl = (const float*)d_in[7];
    const float* bl = (const float*)d_in[8];
    float* out = (float*)d_out;

    const int N = in_sizes[0] / 16;
    const int E = in_sizes[2];
    const int* row = ei;
    const int* col = ei + E;
    const int NB    = (N + 255) / 256;           // node blocks
    const int nbuck = N >> 8;                    // 256 buckets
    const int nsb   = (E + CHUNK - 1) / CHUNK;   // 256 edge blocks (E=1M)
    const int FSZ   = 256 * nsb;                 // 64K scan entries
    const int FB    = (FSZ + 255) / 256;         // 256 scanF1 blocks (<=256 required)

    // workspace layout:
    //  R0: pack (E*4 = 4MB)                 [live: s4 -> end]
    //  R1: bufA = g (N*64*2 = 8MB fp16)     [live: s4 gemv tail -> end]
    //  R2: 16MB region: bufB (h, fp32) ALIASES {tmp 8MB, F 256KB, bsum 1KB}
    //  R3: dinv (256KB), start (256KB+4)
    char* p = (char*)d_ws;
    unsigned* pack = (unsigned*)p;  p += (size_t)E * 4;
    __half*   bufA = (__half*)p;    p += (size_t)N * 64 * 2;
    char*     r2   = p;             p += (size_t)N * 64 * 4;
    float*    dinv = (float*)p;     p += (size_t)N * 4;
    int*    startO = (int*)p;       p += (size_t)(N + 1) * 4;

    int2* tmp  = (int2*)r2;
    int*  F    = (int*)(r2 + (size_t)E * 8);
    int*  bsum = F + FSZ;
    float* bufB = (float*)r2;

    // ---- CSR build via counting sort (no global atomics, coalesced scatters) ----
    s1_hist<<<nsb, 256, 0, stream>>>(col, F, E, nsb);
    scanF1<<<FB, 256, 0, stream>>>(F, bsum, FSZ);
    s3_scatter<<<nsb, 256, 0, stream>>>(col, row, ew, F, bsum, tmp, E, nsb);
    // ---- S4: LDS-resident fine sort + dinv + start + fused layer-1 GEMV (fp16 g1) ----
    s4_fine<<<nbuck, 256, 0, stream>>>(tmp, F, bsum, pack, dinv, startO,
                                       x, W1, bufA, N, E, nsb, nbuck);

    // ---- layer 1 aggregate + relu -> h (fp32) ----
    gather_mid<<<(N + 3) / 4, 256, 0, stream>>>(startO, pack, bufA, dinv, b1, bufB, N);

    // ---- layer 2 GEMM: g2 = dinv*(h@W2) (fp16) ----
    gemm_hid<<<NB, 256, 0, stream>>>(bufB, W2, dinv, bufA, N);

    // ---- layer 2 aggregate + relu + head -> out ----
    gather_head<<<(N + 3) / 4, 256, 0, stream>>>(startO, pack, bufA, dinv, b2, Wl, bl, out, N);
}